// Round 7
// baseline (813.929 us; speedup 1.0000x reference)
//
#include <hip/hip_runtime.h>
#include <math.h>

typedef _Float16 f16x8 __attribute__((ext_vector_type(8)));
typedef _Float16 f16x4 __attribute__((ext_vector_type(4)));
typedef float f32x4 __attribute__((ext_vector_type(4)));

#define MFMA16(a, b, c) __builtin_amdgcn_mfma_f32_16x16x32_f16(a, b, c, 0, 0, 0)

constexpr int L = 1024;
constexpr int D = 64;
constexpr int QT = 16;                        // q rows per tile
constexpr int BH = 128;                       // B*H
constexpr size_t OUT_ELEMS = 8ull * 16 * 1024 * 64;
constexpr size_t PLANE = (size_t)BH * L * D;  // 8,388,608 elems
constexpr size_t BMN   = 8ull * 1024 * 1024;  // B*L*L elems

// fp16-element LDS swizzle: XOR col bits [3:5] (16B blocks) with row&7
__device__ __forceinline__ int swzh(int row, int col) {
    return row * L + (col ^ ((row & 7) << 3));
}

// ---------------- fused prep kernel ----------------
// blocks [0,4096):   K -> fp16 plane (0.125 folded)
// blocks [4096,6144): V [bh][k][d] -> fp16 Vt [bh][d][k]
// blocks [6144,8192): bias+mask -> permuted fp16 bm plane (MFMA D-layout)
__global__ __launch_bounds__(256)
void prep_all(const float* __restrict__ kg, const float* __restrict__ vg,
              const float* __restrict__ bias, const int* __restrict__ mask,
              _Float16* __restrict__ kf, _Float16* __restrict__ vtf,
              _Float16* __restrict__ bmp) {
    __shared__ __align__(16) char smem[16640];
    const int bid = blockIdx.x;
    const int tid = threadIdx.x;

    if (bid < 4096) {
        const size_t t = ((size_t)bid * 256 + tid) * 8;
        float4 a0 = *(const float4*)(kg + t);
        float4 a1 = *(const float4*)(kg + t + 4);
        f16x8 o;
        o[0] = (_Float16)(0.125f * a0.x); o[1] = (_Float16)(0.125f * a0.y);
        o[2] = (_Float16)(0.125f * a0.z); o[3] = (_Float16)(0.125f * a0.w);
        o[4] = (_Float16)(0.125f * a1.x); o[5] = (_Float16)(0.125f * a1.y);
        o[6] = (_Float16)(0.125f * a1.z); o[7] = (_Float16)(0.125f * a1.w);
        *(f16x8*)(kf + t) = o;
    } else if (bid < 6144) {
        _Float16 (*tile)[72] = (_Float16(*)[72])smem;
        const int vb = bid - 4096;
        const int bh = vb >> 4;
        const int k0 = (vb & 15) * 64;
#pragma unroll
        for (int r = 0; r < 4; ++r) {
            const int k  = r * 16 + (tid >> 4);
            const int d0 = (tid & 15) * 4;
            float4 a = *(const float4*)(vg + ((size_t)(bh * L + k0 + k)) * D + d0);
            tile[d0 + 0][k] = (_Float16)a.x;
            tile[d0 + 1][k] = (_Float16)a.y;
            tile[d0 + 2][k] = (_Float16)a.z;
            tile[d0 + 3][k] = (_Float16)a.w;
        }
        __syncthreads();
#pragma unroll
        for (int w = 0; w < 4; ++w) {
            const int d   = w * 16 + (tid >> 4);
            const int kk0 = (tid & 15) * 4;
            const size_t dst = (size_t)bh * (D * L) + (size_t)d * L + k0 + kk0;
            *(f16x4*)(vtf + dst) = *(const f16x4*)&tile[d][kk0];
        }
    } else {
        float (*tile)[260] = (float(*)[260])smem;
        const int wgid = bid - 6144;          // (b*64+qt)*4 + wave
        const int wave = wgid & 3;
        const int bqt  = wgid >> 2;
        const int qt = bqt & 63;
        const int b  = bqt >> 6;
        const size_t rowbase = ((size_t)b * L + qt * 16) * L + wave * 256;
#pragma unroll 4
        for (int rr = 0; rr < 16; ++rr) {
            float bv = bias[rowbase + (size_t)rr * L + tid];
            int   mv = mask[rowbase + (size_t)rr * L + tid];
            tile[rr][tid] = mv ? bv : -1.0f;
        }
        __syncthreads();
        _Float16* out = bmp + (size_t)wgid * 4096;
#pragma unroll
        for (int h = 0; h < 2; ++h) {
            const int vidx = h * 256 + tid;
            const int lam = vidx & 63;
            const int lr = lam & 15, lg = lam >> 4;
            const int g = vidx >> 6;
            f16x8 o;
#pragma unroll
            for (int s = 0; s < 8; ++s) {
                const int slot = g * 8 + s;
                const int ct = slot >> 2, r = slot & 3;
                o[s] = (_Float16)tile[lr][ct * 16 + 4 * lg + r];
            }
            *(f16x8*)(out + (size_t)vidx * 8) = o;
        }
    }
}

// ---------------- main fused kernel: persistent, 8 q-tiles per WG ----------------
__global__ __launch_bounds__(256, 4)
void attn_main(const float* __restrict__ qg, const _Float16* __restrict__ kf_g,
               const _Float16* __restrict__ vtf_g, const _Float16* __restrict__ bmp_g,
               float* __restrict__ outg) {
    __shared__ __align__(16) _Float16 plds[QT * L];   // 32 KiB: P fp16
    __shared__ float red[4][16][2];                   // {local max, local sum}

    // bijective XCD swizzle (1024 % 8 == 0): same-bh WGs land on one XCD
    const int swz = (blockIdx.x & 7) * 128 + (blockIdx.x >> 3);
    const int bh  = swz >> 3;                 // 0..127
    const int sub = swz & 7;                  // 0..7 -> q-tiles sub*8 .. sub*8+7
    const int b   = bh >> 4;
    const int tid  = threadIdx.x;
    const int wave = tid >> 6;
    const int lane = tid & 63;
    const int lg   = lane >> 4;
    const int lr   = lane & 15;

    const float*    qp = qg + (size_t)bh * L * D;
    const _Float16* kp = kf_g + (size_t)bh * L * D;
    const int cbase = wave * 256;
    const int d0 = wave * 16;
    const _Float16* vrow = vtf_g + (size_t)bh * D * L + (size_t)(d0 + lr) * L;

    // Q raw prefetch for tile 0
    float4 qr0, qr1, qr2, qr3;
    {
        const float* src = qp + (size_t)(sub * 8 * QT + lr) * D + lg * 8;
        qr0 = *(const float4*)src;       qr1 = *(const float4*)(src + 4);
        qr2 = *(const float4*)(src + 32); qr3 = *(const float4*)(src + 36);
    }

#pragma unroll 1
    for (int t = 0; t < 8; ++t) {
        const int qt = sub * 8 + t;
        const int q0 = qt * QT;

        // convert prefetched Q raw -> fp16 B-frags
        f16x8 qf0, qf1;
        qf0[0] = (_Float16)qr0.x; qf0[1] = (_Float16)qr0.y;
        qf0[2] = (_Float16)qr0.z; qf0[3] = (_Float16)qr0.w;
        qf0[4] = (_Float16)qr1.x; qf0[5] = (_Float16)qr1.y;
        qf0[6] = (_Float16)qr1.z; qf0[7] = (_Float16)qr1.w;
        qf1[0] = (_Float16)qr2.x; qf1[1] = (_Float16)qr2.y;
        qf1[2] = (_Float16)qr2.z; qf1[3] = (_Float16)qr2.w;
        qf1[4] = (_Float16)qr3.x; qf1[5] = (_Float16)qr3.y;
        qf1[6] = (_Float16)qr3.z; qf1[7] = (_Float16)qr3.w;

        // ---- swapped QK^T: acc[ct] = S for q=q0+lr, keys cbase+16ct+4lg+r ----
        f32x4 acc[16];
#pragma unroll
        for (int ct = 0; ct < 16; ++ct) {
            const _Float16* krow = kp + (size_t)(cbase + ct * 16 + lr) * D + lg * 8;
            f16x8 kv0 = *(const f16x8*)(krow);
            f16x8 kv1 = *(const f16x8*)(krow + 32);
            f32x4 a = {0.f, 0.f, 0.f, 0.f};
            a = MFMA16(kv0, qf0, a);
            a = MFMA16(kv1, qf1, a);
            acc[ct] = a;
        }

        // ---- bias*mask apply (L2-resident permuted plane) ----
        const _Float16* bmr = bmp_g + ((size_t)(b * 64 + qt) * 4 + wave) * 4096;
#pragma unroll
        for (int g = 0; g < 8; ++g) {
            f16x8 bv = *(const f16x8*)(bmr + g * 512 + lane * 8);
#pragma unroll
            for (int s = 0; s < 8; ++s) {
                float tt = (float)bv[s];
                float a = acc[2 * g + (s >> 2)][s & 3];
                acc[2 * g + (s >> 2)][s & 3] = (tt >= 0.f) ? a * tt : -INFINITY;
            }
        }

        // ---- in-register softmax over the wave's 256-key chunk ----
        float m = -INFINITY;
#pragma unroll
        for (int ct = 0; ct < 16; ++ct)
#pragma unroll
            for (int r = 0; r < 4; ++r) m = fmaxf(m, acc[ct][r]);
        m = fmaxf(m, __shfl_xor(m, 16));
        m = fmaxf(m, __shfl_xor(m, 32));
        m = fmaxf(m, -10000.0f);              // guard all-masked chunk

        float lsum = 0.f;
#pragma unroll
        for (int ct = 0; ct < 16; ++ct)
#pragma unroll
            for (int r = 0; r < 4; ++r) {
                float p = __expf(acc[ct][r] - m);
                acc[ct][r] = p;
                lsum += p;
            }
        lsum += __shfl_xor(lsum, 16);
        lsum += __shfl_xor(lsum, 32);

        if (lg == 0) { red[wave][lr][0] = m; red[wave][lr][1] = lsum; }
        __syncthreads();                      // also protects plds reuse (see PV(t-1))

        float M = -INFINITY;
#pragma unroll
        for (int w = 0; w < 4; ++w) M = fmaxf(M, red[w][lr][0]);
        float denom = 0.f;
#pragma unroll
        for (int w = 0; w < 4; ++w) denom += red[w][lr][1] * __expf(red[w][lr][0] - M);
        denom = fmaxf(denom, 1e-37f);
        const float scale = __expf(m - M) / denom;

        // ---- P -> LDS fp16 (normalized) ----
#pragma unroll
        for (int ct = 0; ct < 16; ++ct) {
            f16x4 pv;
#pragma unroll
            for (int r = 0; r < 4; ++r) pv[r] = (_Float16)(acc[ct][r] * scale);
            *(f16x4*)&plds[swzh(lr, cbase + ct * 16 + 4 * lg)] = pv;
        }
        __syncthreads();

        // ---- PV group-0 prefetch (V latency hides under score stores) ----
        f16x8 paf[2][4], vbf[2][4];
#pragma unroll
        for (int j = 0; j < 4; ++j) {
            const int e0 = j * 32 + lg * 8;
            paf[0][j] = *(const f16x8*)&plds[swzh(lr, e0)];
            vbf[0][j] = *(const f16x8*)(vrow + e0);
        }

        // ---- next tile's Q raw prefetch ----
        if (t < 7) {
            const float* src = qp + (size_t)((q0 + QT) + lr) * D + lg * 8;
            qr0 = *(const float4*)src;       qr1 = *(const float4*)(src + 4);
            qr2 = *(const float4*)(src + 32); qr3 = *(const float4*)(src + 36);
        }

        // ---- score write: wave w owns rows 4w..4w+3; NT 1KB/instr ----
        float* srow0 = outg + OUT_ELEMS + (size_t)bh * L * L
                     + (size_t)(q0 + wave * 4) * L;
#pragma unroll
        for (int rr = 0; rr < 4; ++rr) {
#pragma unroll
            for (int mt = 0; mt < 4; ++mt) {
                const int col = mt * 256 + lane * 4;
                f16x4 pv = *(const f16x4*)&plds[swzh(wave * 4 + rr, col)];
                f32x4 o = {(float)pv[0], (float)pv[1], (float)pv[2], (float)pv[3]};
                __builtin_nontemporal_store(o, (f32x4*)(srow0 + (size_t)rr * L + col));
            }
        }

        // ---- PV: wave w owns d cols [16w,16w+16); depth-1 group prefetch ----
        f32x4 oacc = {0.f, 0.f, 0.f, 0.f};
#pragma unroll
        for (int g = 0; g < 8; ++g) {
            const int cur = g & 1, nxt = cur ^ 1;
            if (g < 7) {
#pragma unroll
                for (int j = 0; j < 4; ++j) {
                    const int e0 = (g + 1) * 128 + j * 32 + lg * 8;
                    paf[nxt][j] = *(const f16x8*)&plds[swzh(lr, e0)];
                    vbf[nxt][j] = *(const f16x8*)(vrow + e0);
                }
            }
#pragma unroll
            for (int j = 0; j < 4; ++j) oacc = MFMA16(paf[cur][j], vbf[cur][j], oacc);
        }
#pragma unroll
        for (int r = 0; r < 4; ++r) {
            __builtin_nontemporal_store(
                oacc[r], outg + ((size_t)bh * L + q0 + lg * 4 + r) * D + d0 + lr);
        }
    }
}

extern "C" void kernel_launch(void* const* d_in, const int* in_sizes, int n_in,
                              void* d_out, int out_size, void* d_ws, size_t ws_size,
                              hipStream_t stream) {
    const float* q    = (const float*)d_in[0];
    const float* k    = (const float*)d_in[1];
    const float* v    = (const float*)d_in[2];
    const float* bias = (const float*)d_in[3];
    const int*   mask = (const int*)d_in[4];
    float* out = (float*)d_out;

    const size_t need = (2 * PLANE + BMN) * sizeof(_Float16);   // ~50 MiB
    if (ws_size < need) return;               // empirically ws_size >= 64 MiB

    _Float16* kf  = (_Float16*)d_ws;          // [BH][L][D] fp16, pre-scaled 0.125
    _Float16* vtf = kf + PLANE;               // [BH][D][L] fp16
    _Float16* bmp = vtf + PLANE;              // permuted fp16 bias/mask plane

    hipLaunchKernelGGL(prep_all, dim3(8192), dim3(256), 0, stream,
                       k, v, bias, mask, kf, vtf, bmp);
    hipLaunchKernelGGL(attn_main, dim3(1024), dim3(256), 0, stream,
                       q, kf, vtf, bmp, out);
}

// Round 8
// 372.166 us; speedup vs baseline: 2.1870x; 2.1870x over previous
//
#include <hip/hip_runtime.h>
#include <math.h>

typedef _Float16 f16x8 __attribute__((ext_vector_type(8)));
typedef _Float16 f16x4 __attribute__((ext_vector_type(4)));
typedef float f32x4 __attribute__((ext_vector_type(4)));

#define MFMA16(a, b, c) __builtin_amdgcn_mfma_f32_16x16x32_f16(a, b, c, 0, 0, 0)

constexpr int L = 1024;
constexpr int D = 64;
constexpr int QT = 16;                        // q rows per workgroup
constexpr int BH = 128;                       // B*H
constexpr size_t OUT_ELEMS = 8ull * 16 * 1024 * 64;
constexpr size_t PLANE = (size_t)BH * L * D;  // 8,388,608 elems
constexpr size_t BMN   = 8ull * 1024 * 1024;  // B*L*L elems

// fp16-element LDS swizzle: XOR col bits [3:5] (16B blocks) with row&7
__device__ __forceinline__ int swzh(int row, int col) {
    return row * L + (col ^ ((row & 7) << 3));
}

// ---------------- fused prep kernel ----------------
// blocks [0,4096):     K -> fp16 plane (0.125 folded)
// blocks [4096,6144):  V [bh][k][d] -> fp16 Vt [bh][d][k]
// blocks [6144,10240): bias+mask -> permuted fp16 bm plane (8-wave MFMA D-layout)
__global__ __launch_bounds__(256)
void prep_all(const float* __restrict__ kg, const float* __restrict__ vg,
              const float* __restrict__ bias, const int* __restrict__ mask,
              _Float16* __restrict__ kf, _Float16* __restrict__ vtf,
              _Float16* __restrict__ bmp) {
    __shared__ __align__(16) char smem[16640];
    const int bid = blockIdx.x;
    const int tid = threadIdx.x;

    if (bid < 4096) {
        const size_t t = ((size_t)bid * 256 + tid) * 8;
        float4 a0 = *(const float4*)(kg + t);
        float4 a1 = *(const float4*)(kg + t + 4);
        f16x8 o;
        o[0] = (_Float16)(0.125f * a0.x); o[1] = (_Float16)(0.125f * a0.y);
        o[2] = (_Float16)(0.125f * a0.z); o[3] = (_Float16)(0.125f * a0.w);
        o[4] = (_Float16)(0.125f * a1.x); o[5] = (_Float16)(0.125f * a1.y);
        o[6] = (_Float16)(0.125f * a1.z); o[7] = (_Float16)(0.125f * a1.w);
        *(f16x8*)(kf + t) = o;
    } else if (bid < 6144) {
        _Float16 (*tile)[72] = (_Float16(*)[72])smem;
        const int vb = bid - 4096;
        const int bh = vb >> 4;
        const int k0 = (vb & 15) * 64;
#pragma unroll
        for (int r = 0; r < 4; ++r) {
            const int k  = r * 16 + (tid >> 4);
            const int d0 = (tid & 15) * 4;
            float4 a = *(const float4*)(vg + ((size_t)(bh * L + k0 + k)) * D + d0);
            tile[d0 + 0][k] = (_Float16)a.x;
            tile[d0 + 1][k] = (_Float16)a.y;
            tile[d0 + 2][k] = (_Float16)a.z;
            tile[d0 + 3][k] = (_Float16)a.w;
        }
        __syncthreads();
#pragma unroll
        for (int w = 0; w < 4; ++w) {
            const int d   = w * 16 + (tid >> 4);
            const int kk0 = (tid & 15) * 4;
            const size_t dst = (size_t)bh * (D * L) + (size_t)d * L + k0 + kk0;
            *(f16x4*)(vtf + dst) = *(const f16x4*)&tile[d][kk0];
        }
    } else {
        // ---- conv_bm: region per (b,qt,w8): 2048 fp16 (16 rows x 128 keys) ----
        float (*tile)[132] = (float(*)[132])smem;
        const int wgid = bid - 6144;          // (b*64+qt)*8 + w
        const int w    = wgid & 7;
        const int bqt  = wgid >> 3;
        const int qt = bqt & 63;
        const int b  = bqt >> 6;
        const size_t rowbase = ((size_t)b * L + qt * 16) * L + w * 128;
#pragma unroll
        for (int h = 0; h < 8; ++h) {
            const int idx = h * 256 + tid;
            const int row = idx >> 7, col = idx & 127;
            float bv = bias[rowbase + (size_t)row * L + col];
            int   mv = mask[rowbase + (size_t)row * L + col];
            tile[row][col] = mv ? bv : -1.0f;
        }
        __syncthreads();
        _Float16* out = bmp + (size_t)wgid * 2048;
        const int lam = tid & 63;
        const int lr = lam & 15, lg = lam >> 4;
        const int g = tid >> 6;               // 0..3
        f16x8 o;
#pragma unroll
        for (int s = 0; s < 8; ++s) {
            const int slot = g * 8 + s;       // = ct*4 + r, ct in [0,8)
            const int ct = slot >> 2, r = slot & 3;
            o[s] = (_Float16)tile[lr][ct * 16 + 4 * lg + r];
        }
        *(f16x8*)(out + (size_t)tid * 8) = o;
    }
}

// ------------- main fused kernel: 8 waves, specialized PV/score phases -------------
__global__ __launch_bounds__(512, 6)
void attn_main(const float* __restrict__ qg, const _Float16* __restrict__ kf_g,
               const _Float16* __restrict__ vtf_g, const _Float16* __restrict__ bmp_g,
               float* __restrict__ outg) {
    __shared__ __align__(16) _Float16 plds[QT * L];   // 32 KiB: P fp16
    __shared__ float red[8][16][2];                   // {local max, local sum}

    // bijective XCD swizzle: 8192 % 8 == 0
    const int wg = (blockIdx.x & 7) * 1024 + (blockIdx.x >> 3);
    const int bh = wg >> 6;
    const int qt = wg & 63;
    const int b  = bh >> 4;
    const int q0 = qt * QT;
    const int tid  = threadIdx.x;
    const int wave = tid >> 6;                // 0..7
    const int lane = tid & 63;
    const int lg   = lane >> 4;
    const int lr   = lane & 15;

    const float*    qp = qg + (size_t)bh * L * D;
    const _Float16* kp = kf_g + (size_t)bh * L * D;
    const int kbase = wave * 128;             // this wave's 128-key chunk

    // Q as B-frag: col(q) = lr -> row q0+lr, k(d) = lg*8 + j
    f16x8 qf0, qf1;
    {
        const float* src = qp + (size_t)(q0 + lr) * D + lg * 8;
        float4 a0 = *(const float4*)src;
        float4 a1 = *(const float4*)(src + 4);
        float4 a2 = *(const float4*)(src + 32);
        float4 a3 = *(const float4*)(src + 36);
        qf0[0] = (_Float16)a0.x; qf0[1] = (_Float16)a0.y;
        qf0[2] = (_Float16)a0.z; qf0[3] = (_Float16)a0.w;
        qf0[4] = (_Float16)a1.x; qf0[5] = (_Float16)a1.y;
        qf0[6] = (_Float16)a1.z; qf0[7] = (_Float16)a1.w;
        qf1[0] = (_Float16)a2.x; qf1[1] = (_Float16)a2.y;
        qf1[2] = (_Float16)a2.z; qf1[3] = (_Float16)a2.w;
        qf1[4] = (_Float16)a3.x; qf1[5] = (_Float16)a3.y;
        qf1[6] = (_Float16)a3.z; qf1[7] = (_Float16)a3.w;
    }

    // ---- swapped QK^T: acc[ct] = S for q=q0+lr, keys kbase+16ct+4lg+r ----
    f32x4 acc[8];
#pragma unroll
    for (int ct = 0; ct < 8; ++ct) {
        const _Float16* krow = kp + (size_t)(kbase + ct * 16 + lr) * D + lg * 8;
        f16x8 kv0 = *(const f16x8*)(krow);
        f16x8 kv1 = *(const f16x8*)(krow + 32);
        f32x4 a = {0.f, 0.f, 0.f, 0.f};
        a = MFMA16(kv0, qf0, a);
        a = MFMA16(kv1, qf1, a);
        acc[ct] = a;
    }

    // ---- bias*mask apply (L2-resident permuted plane) ----
    const _Float16* bmr = bmp_g + ((size_t)(b * 64 + qt) * 8 + wave) * 2048;
#pragma unroll
    for (int g = 0; g < 4; ++g) {
        f16x8 bv = *(const f16x8*)(bmr + g * 512 + lane * 8);
#pragma unroll
        for (int s = 0; s < 8; ++s) {
            const int slot = g * 8 + s;
            float tt = (float)bv[s];
            float a = acc[slot >> 2][slot & 3];
            acc[slot >> 2][slot & 3] = (tt >= 0.f) ? a * tt : -INFINITY;
        }
    }

    // ---- in-register softmax over the wave's 128-key chunk ----
    float m = -INFINITY;
#pragma unroll
    for (int ct = 0; ct < 8; ++ct)
#pragma unroll
        for (int r = 0; r < 4; ++r) m = fmaxf(m, acc[ct][r]);
    m = fmaxf(m, __shfl_xor(m, 16));
    m = fmaxf(m, __shfl_xor(m, 32));
    m = fmaxf(m, -10000.0f);                  // guard all-masked chunk

    float lsum = 0.f;
#pragma unroll
    for (int ct = 0; ct < 8; ++ct)
#pragma unroll
        for (int r = 0; r < 4; ++r) {
            float p = __expf(acc[ct][r] - m);  // exp(-inf)=0 for masked
            acc[ct][r] = p;
            lsum += p;
        }
    lsum += __shfl_xor(lsum, 16);
    lsum += __shfl_xor(lsum, 32);

    if (lg == 0) { red[wave][lr][0] = m; red[wave][lr][1] = lsum; }
    __syncthreads();

    float M = -INFINITY;
#pragma unroll
    for (int w = 0; w < 8; ++w) M = fmaxf(M, red[w][lr][0]);
    float denom = 0.f;
#pragma unroll
    for (int w = 0; w < 8; ++w) denom += red[w][lr][1] * __expf(red[w][lr][0] - M);
    denom = fmaxf(denom, 1e-37f);
    const float scale = __expf(m - M) / denom;

    // ---- P -> LDS fp16 (normalized) ----
#pragma unroll
    for (int ct = 0; ct < 8; ++ct) {
        f16x4 pv;
#pragma unroll
        for (int r = 0; r < 4; ++r) pv[r] = (_Float16)(acc[ct][r] * scale);
        *(f16x4*)&plds[swzh(lr, kbase + ct * 16 + 4 * lg)] = pv;
    }
    __syncthreads();

    if (wave < 4) {
        // ---- PV: wave w owns d cols [16w,16w+16) over all 1024 keys ----
        const int d0 = wave * 16;
        const _Float16* vrow = vtf_g + (size_t)bh * D * L + (size_t)(d0 + lr) * L;
        f32x4 oacc = {0.f, 0.f, 0.f, 0.f};
#pragma unroll
        for (int kb = 0; kb < L; kb += 32) {
            const int e0 = kb + lg * 8;
            f16x8 pa = *(const f16x8*)&plds[swzh(lr, e0)];
            f16x8 vb = *(const f16x8*)(vrow + e0);
            oacc = MFMA16(pa, vb, oacc);
        }
#pragma unroll
        for (int r = 0; r < 4; ++r) {
            outg[((size_t)bh * L + q0 + lg * 4 + r) * D + d0 + lr] = oacc[r];
        }
    } else {
        // ---- score store: wave w owns rows 4(w-4)..4(w-4)+3; 1KB/instr ----
        const int row0 = (wave - 4) * 4;
        float* srow0 = outg + OUT_ELEMS + (size_t)bh * L * L
                     + (size_t)(q0 + row0) * L;
#pragma unroll
        for (int rr = 0; rr < 4; ++rr) {
#pragma unroll
            for (int mt = 0; mt < 4; ++mt) {
                const int col = mt * 256 + lane * 4;
                f16x4 pv = *(const f16x4*)&plds[swzh(row0 + rr, col)];
                f32x4 o = {(float)pv[0], (float)pv[1], (float)pv[2], (float)pv[3]};
                *(f32x4*)(srow0 + (size_t)rr * L + col) = o;
            }
        }
    }
}

extern "C" void kernel_launch(void* const* d_in, const int* in_sizes, int n_in,
                              void* d_out, int out_size, void* d_ws, size_t ws_size,
                              hipStream_t stream) {
    const float* q    = (const float*)d_in[0];
    const float* k    = (const float*)d_in[1];
    const float* v    = (const float*)d_in[2];
    const float* bias = (const float*)d_in[3];
    const int*   mask = (const int*)d_in[4];
    float* out = (float*)d_out;

    const size_t need = (2 * PLANE + BMN) * sizeof(_Float16);   // ~50 MiB
    if (ws_size < need) return;               // empirically ws_size >= 64 MiB

    _Float16* kf  = (_Float16*)d_ws;          // [BH][L][D] fp16, pre-scaled 0.125
    _Float16* vtf = kf + PLANE;               // [BH][D][L] fp16
    _Float16* bmp = vtf + PLANE;              // permuted fp16 bias/mask plane

    hipLaunchKernelGGL(prep_all, dim3(10240), dim3(256), 0, stream,
                       k, v, bias, mask, kf, vtf, bmp);
    hipLaunchKernelGGL(attn_main, dim3(BH * (L / QT)), dim3(512), 0, stream,
                       q, kf, vtf, bmp, out);
}